// Round 1
// baseline (283.646 us; speedup 1.0000x reference)
//
#include <hip/hip_runtime.h>
#include <hip/hip_bf16.h>

#define B_ 2
#define S_ 2048
#define D_ 768
#define H_ 12
#define DH_ 64
#define M_ (B_*S_)     // 4096
#define BH_ (B_*H_)    // 24

typedef __bf16 v8bf __attribute__((ext_vector_type(8)));
typedef __bf16 v4bf __attribute__((ext_vector_type(4)));
typedef float  v4f  __attribute__((ext_vector_type(4)));

static __device__ __forceinline__ v4f mfma16(v8bf a, v8bf b, v4f c) {
  return __builtin_amdgcn_mfma_f32_16x16x32_bf16(a, b, c, 0, 0, 0);
}

// async global->LDS, 16 B/lane; dest = wave-uniform base + lane*16
static __device__ __forceinline__ void gload_lds16(const __bf16* g, __bf16* l) {
  __builtin_amdgcn_global_load_lds(
      (const __attribute__((address_space(1))) unsigned int*)g,
      (__attribute__((address_space(3))) unsigned int*)l,
      16, 0, 0);
}

#define C1_ 0.18033688011112042f   // log2(e)/sqrt(DH)

// ---------------- fp32 -> bf16 conversion ----------------
__global__ __launch_bounds__(256) void convert_kernel(
    const float* __restrict__ q, const float* __restrict__ k, const float* __restrict__ v,
    const float* __restrict__ Wq, const float* __restrict__ Wk,
    const float* __restrict__ Wv, const float* __restrict__ Wo,
    __bf16* __restrict__ Xq, __bf16* __restrict__ Xk, __bf16* __restrict__ Xv,
    __bf16* __restrict__ Wqb, __bf16* __restrict__ Wkb,
    __bf16* __restrict__ Wvb, __bf16* __restrict__ Wob)
{
  const float* src; __bf16* dst; int n;
  switch (blockIdx.y) {
    case 0: src = q;  dst = Xq;  n = M_*D_; break;
    case 1: src = k;  dst = Xk;  n = M_*D_; break;
    case 2: src = v;  dst = Xv;  n = M_*D_; break;
    case 3: src = Wq; dst = Wqb; n = D_*D_; break;
    case 4: src = Wk; dst = Wkb; n = D_*D_; break;
    case 5: src = Wv; dst = Wvb; n = D_*D_; break;
    default: src = Wo; dst = Wob; n = D_*D_; break;
  }
  int n4 = n >> 2;
  for (int i = blockIdx.x*blockDim.x + threadIdx.x; i < n4; i += gridDim.x*blockDim.x) {
    float4 x = ((const float4*)src)[i];
    v4bf y;
    y[0] = (__bf16)x.x; y[1] = (__bf16)x.y; y[2] = (__bf16)x.z; y[3] = (__bf16)x.w;
    ((v4bf*)dst)[i] = y;
  }
}

// ---------------- em precompute: em = bf16(exp2(C1*mask)) in attn-lane order ----------------
// flat t = (((qt*64 + ktile)*4 + qq)*64 + L); elem t*8 + (half*4 + r) holds
// exp2(C1*mask[qt*64+qq*16+(L&15)][ktile*32+half*16+(L>>4)*4+r]).
// (one v8bf per (qq,lane) in the attn inner loop)
__global__ __launch_bounds__(256) void em_kernel(
    const float* __restrict__ mask, __bf16* __restrict__ em)
{
  int t = blockIdx.x*256 + threadIdx.x;        // 0 .. 524287
  int L = t & 63; int rest = t >> 6;
  int qq = rest & 3; rest >>= 2;
  int ktile = rest & 63; rest >>= 6;
  int qt = rest;                                // 0..31
  int row = qt*64 + qq*16 + (L & 15);
  int key0 = ktile*32 + ((L >> 4) << 2);
  const float* mp = mask + (size_t)row*S_ + key0;
  float4 m0 = *(const float4*)mp;
  float4 m1 = *(const float4*)(mp + 16);
  v8bf e;
  e[0] = (__bf16)exp2f(C1_*m0.x); e[1] = (__bf16)exp2f(C1_*m0.y);
  e[2] = (__bf16)exp2f(C1_*m0.z); e[3] = (__bf16)exp2f(C1_*m0.w);
  e[4] = (__bf16)exp2f(C1_*m1.x); e[5] = (__bf16)exp2f(C1_*m1.y);
  e[6] = (__bf16)exp2f(C1_*m1.z); e[7] = (__bf16)exp2f(C1_*m1.w);
  *(v8bf*)(em + (size_t)t*8) = e;
}

// ---------------- templated LDS-staged NT-GEMM core: C[BMxBN] = A @ W^T ----------------
template<int BM, int BN>
static __device__ __forceinline__ void gemm_core_lds(
    const __bf16* __restrict__ A, const __bf16* __restrict__ W,
    int m0, int n0, __bf16* lds, v4f acc[BM/32][BN/32])
{
  constexpr int NFA = BM/16, NFB = BN/16;
  constexpr int PW  = (NFA + NFB) / 4;
  constexpr int MI  = BM/32, NJ = BN/32;
  const int lane = threadIdx.x & 63;
  const int wave = threadIdx.x >> 6;
  const int r16 = lane & 15;
  const int kc8 = (lane >> 4) << 3;
  const int ia = (wave >> 1) * MI;
  const int ib = (wave & 1) * NJ;

  const __bf16* gsrc[PW]; __bf16* ldst[PW];
  #pragma unroll
  for (int t = 0; t < PW; t++) {
    int fb = wave*PW + t;
    gsrc[t] = (fb < NFA)
        ? A + (size_t)(m0 + fb*16 + r16)*D_ + kc8
        : W + (size_t)(n0 + (fb - NFA)*16 + r16)*D_ + kc8;
    ldst[t] = lds + fb*512;
  }

  for (int k0 = 0; k0 < D_; k0 += 32) {
    #pragma unroll
    for (int t = 0; t < PW; t++) gload_lds16(gsrc[t] + k0, ldst[t]);
    __syncthreads();
    v8bf a[MI], b[NJ];
    #pragma unroll
    for (int i = 0; i < MI; i++) a[i] = *(const v8bf*)(lds + (ia+i)*512 + lane*8);
    #pragma unroll
    for (int j = 0; j < NJ; j++) b[j] = *(const v8bf*)(lds + (NFA+ib+j)*512 + lane*8);
    #pragma unroll
    for (int i = 0; i < MI; i++)
      #pragma unroll
      for (int j = 0; j < NJ; j++)
        acc[i][j] = mfma16(a[i], b[j], acc[i][j]);
    __syncthreads();
  }
}

// ---------------- QKV projection (128x64 tiles) -> FRAGMENT-ORDERED qf/kf/vf ----------------
// qf/kf: per bh, per s16-block, per half: 512 elems; elem[lane*8+j] =
//   X[s16*16+(lane&15)][half*32+(lane>>4)*8+j].   (B-op for Q, A-op for K: same formula)
// qf additionally carries the C1 = log2(e)/sqrt(DH) scale (folded in fp32 before bf16 round).
// vf: per bh, per ktile32, per f: 512 elems; elem[lane*8+j] =
//   V[ktile*32+(lane>>4)*8+j][f*16+(lane&15)].
__global__ __launch_bounds__(256) void qkv_gemm(
    const __bf16* __restrict__ Xq, const __bf16* __restrict__ Xk, const __bf16* __restrict__ Xv,
    const __bf16* __restrict__ Wqb, const __bf16* __restrict__ Wkb, const __bf16* __restrict__ Wvb,
    const float* __restrict__ bq, const float* __restrict__ bk, const float* __restrict__ bv,
    __bf16* __restrict__ qf, __bf16* __restrict__ kf, __bf16* __restrict__ vf)
{
  __shared__ __bf16 lds[(128+64)*32];   // 12 KB
  const int mode = blockIdx.z;
  const __bf16* A = (mode == 0) ? Xq : (mode == 1) ? Xk : Xv;
  const __bf16* W = (mode == 0) ? Wqb : (mode == 1) ? Wkb : Wvb;
  const float* bias = (mode == 0) ? bq : (mode == 1) ? bk : bv;
  const int m0 = blockIdx.y << 7, n0 = blockIdx.x << 6;
  v4f acc[4][2];
  #pragma unroll
  for (int i = 0; i < 4; i++)
    #pragma unroll
    for (int j = 0; j < 2; j++) { v4f z = {0.f,0.f,0.f,0.f}; acc[i][j] = z; }
  gemm_core_lds<128,64>(A, W, m0, n0, lds, acc);

  const int lane = threadIdx.x & 63;
  const int wave = threadIdx.x >> 6;
  const int wm = (wave >> 1) << 6, wn = (wave & 1) << 5;
  const int col = lane & 15, quad = lane >> 4;
  float bb[2]; int nn[2];
  #pragma unroll
  for (int j = 0; j < 2; j++) { nn[j] = n0 + wn + 16*j + col; bb[j] = bias[nn[j]]; }

  if (mode < 2) {
    __bf16* dst = (mode == 0) ? qf : kf;
    const float sc = (mode == 0) ? C1_ : 1.0f;
    #pragma unroll
    for (int i = 0; i < 4; i++)
      #pragma unroll
      for (int r = 0; r < 4; r++) {
        int m = m0 + wm + 16*i + quad*4 + r;
        int batch = m >> 11, s = m & (S_-1);
        #pragma unroll
        for (int j = 0; j < 2; j++) {
          int n = nn[j];
          int h = n >> 6, dd = n & 63;
          size_t flat = (((size_t)(batch*H_ + h)*128 + (s >> 4))*2 + (dd >> 5))*512
                      + ((((dd >> 3) & 3)*16 + (s & 15)) << 3) + (dd & 7);
          dst[flat] = (__bf16)((acc[i][j][r] + bb[j]) * sc);
        }
      }
  } else {
    #pragma unroll
    for (int i = 0; i < 4; i++) {
      int mbase = m0 + wm + 16*i + quad*4;
      int batch = mbase >> 11, s0 = mbase & (S_-1);
      #pragma unroll
      for (int j = 0; j < 2; j++) {
        int n = nn[j];
        int h = n >> 6, dd = n & 63;
        v4bf pk;
        #pragma unroll
        for (int r = 0; r < 4; r++) pk[r] = (__bf16)(acc[i][j][r] + bb[j]);
        size_t flat = (((size_t)(batch*H_ + h)*64 + (s0 >> 5))*4 + (dd >> 4))*512
                    + ((((s0 >> 3) & 3)*16 + (dd & 15)) << 3) + (s0 & 7);
        *(v4bf*)(vf + flat) = pk;
      }
    }
  }
}

// ---------------- flash attention: 64 q/block, split-K, fragment-ordered loads ----------------
// Latency-hiding structure: K tile register-double-buffered across iterations (prefetch of
// step t+1 issues right after step t's QK consumes the current K regs); V + em loads hoisted
// to the top of the step so their latency hides under QK+softmax.  Q pre-scaled by C1 in the
// projection, so p = exp2(s) * em with no per-score multiply.  __launch_bounds__(256,3):
// grid caps residency at 3 blocks/CU anyway, so let the allocator use ~170 VGPRs.
__global__ __launch_bounds__(256, 3) void attn_kernel(
    const __bf16* __restrict__ qf, const __bf16* __restrict__ kf, const __bf16* __restrict__ vf,
    const __bf16* __restrict__ em, __bf16* __restrict__ ao)
{
  __shared__ __bf16 plds[4][4][16][40];  // [wave][qq][q within group][32 keys padded]
  __shared__ float ls[4][64];            // [wave][query] partial l
  __shared__ float Ored[64][68];         // [query][d] fp32 combine buffer

  const int bh = blockIdx.y;
  const int wave = threadIdx.x >> 6, lane = threadIdx.x & 63;
  const int col = lane & 15, quad = lane >> 4, koff = quad << 3;
  const int q0 = blockIdx.x << 6;
  const int batch = bh / H_, h = bh % H_;
  const __bf16* qfb = qf + (size_t)bh * (S_*DH_);
  const __bf16* kfb = kf + (size_t)bh * (S_*DH_);
  const __bf16* vfb = vf + (size_t)bh * (S_*DH_);
  const __bf16* emb = em + (size_t)(q0 >> 6) * 131072;   // per q-tile: 64kt*4qq*512
  __bf16 (*pt)[16][40] = plds[wave];

  v8bf Qf[4][2];
  #pragma unroll
  for (int qq = 0; qq < 4; qq++) {
    const __bf16* qblk = qfb + (size_t)((q0 >> 4) + qq)*1024;
    Qf[qq][0] = *(const v8bf*)(qblk + lane*8);
    Qf[qq][1] = *(const v8bf*)(qblk + 512 + lane*8);
  }

  v4f O[4][4];
  #pragma unroll
  for (int f = 0; f < 4; f++)
    #pragma unroll
    for (int qq = 0; qq < 4; qq++) { v4f z = {0.f,0.f,0.f,0.f}; O[f][qq] = z; }
  float li[4];
  #pragma unroll
  for (int qq = 0; qq < 4; qq++) li[qq] = 0.f;

  const int kbeg = wave << 9;

  // prime the K double-buffer
  const __bf16* kblk0 = kfb + (size_t)(kbeg >> 4)*1024;
  v8bf Ka0 = *(const v8bf*)(kblk0 + lane*8);
  v8bf Ka1 = *(const v8bf*)(kblk0 + 512 + lane*8);
  v8bf Ka2 = *(const v8bf*)(kblk0 + 1024 + lane*8);
  v8bf Ka3 = *(const v8bf*)(kblk0 + 1536 + lane*8);

  #pragma unroll 1
  for (int kt = kbeg; kt < kbeg + 512; kt += 32) {
    // V loads for THIS step, issued early (consumed at the end of the step)
    const __bf16* vblk = vfb + (size_t)(kt >> 5)*2048;
    v8bf Vf0 = *(const v8bf*)(vblk + lane*8);
    v8bf Vf1 = *(const v8bf*)(vblk + 512 + lane*8);
    v8bf Vf2 = *(const v8bf*)(vblk + 1024 + lane*8);
    v8bf Vf3 = *(const v8bf*)(vblk + 1536 + lane*8);
    const __bf16* eblk = emb + (size_t)(kt >> 5)*2048;   // 4qq*512

    // per-qq: QK^T (consumes current K regs) + softmax + P->LDS
    #pragma unroll
    for (int qq = 0; qq < 4; qq++) {
      v8bf ef = *(const v8bf*)(eblk + qq*512 + lane*8);
      v4f s0 = {0.f,0.f,0.f,0.f}, s1 = {0.f,0.f,0.f,0.f};
      s0 = mfma16(Ka0, Qf[qq][0], s0); s0 = mfma16(Ka1, Qf[qq][1], s0);
      s1 = mfma16(Ka2, Qf[qq][0], s1); s1 = mfma16(Ka3, Qf[qq][1], s1);

      float p[8], rs = 0.f;
      #pragma unroll
      for (int j = 0; j < 4; j++) {
        p[j]   = exp2f(s0[j]) * (float)ef[j];
        p[4+j] = exp2f(s1[j]) * (float)ef[4+j];
      }
      #pragma unroll
      for (int j = 0; j < 8; j++) rs += p[j];
      li[qq] += rs;
      v4bf pk0, pk1;
      #pragma unroll
      for (int r = 0; r < 4; r++) { pk0[r] = (__bf16)p[r]; pk1[r] = (__bf16)p[4+r]; }
      *(v4bf*)(&pt[qq][col][quad*4])      = pk0;
      *(v4bf*)(&pt[qq][col][16 + quad*4]) = pk1;
    }

    // cross-iteration prefetch of the next K tile (current regs now dead)
    if (kt + 32 < kbeg + 512) {
      const __bf16* nk = kfb + (size_t)((kt + 32) >> 4)*1024;
      Ka0 = *(const v8bf*)(nk + lane*8);
      Ka1 = *(const v8bf*)(nk + 512 + lane*8);
      Ka2 = *(const v8bf*)(nk + 1024 + lane*8);
      Ka3 = *(const v8bf*)(nk + 1536 + lane*8);
    }

    v8bf Pf[4];
    #pragma unroll
    for (int qq = 0; qq < 4; qq++) Pf[qq] = *(const v8bf*)(&pt[qq][col][koff]);
    #pragma unroll
    for (int qq = 0; qq < 4; qq++) {
      O[0][qq] = mfma16(Vf0, Pf[qq], O[0][qq]);
      O[1][qq] = mfma16(Vf1, Pf[qq], O[1][qq]);
      O[2][qq] = mfma16(Vf2, Pf[qq], O[2][qq]);
      O[3][qq] = mfma16(Vf3, Pf[qq], O[3][qq]);
    }
  }

  // ---- deferred l reduction ----
  #pragma unroll
  for (int qq = 0; qq < 4; qq++) {
    float rs = li[qq];
    rs += __shfl_xor(rs, 16);
    rs += __shfl_xor(rs, 32);
    if (quad == 0) ls[wave][16*qq + col] = rs;
  }
  __syncthreads();

  // ---- in-block split-K combine: plain sums ----
  for (int w = 0; w < 4; w++) {
    if (wave == w) {
      #pragma unroll
      for (int qq = 0; qq < 4; qq++)
        #pragma unroll
        for (int f = 0; f < 4; f++) {
          float4* dst = (float4*)&Ored[16*qq + col][16*f + quad*4];
          float4 val;
          val.x = O[f][qq][0]; val.y = O[f][qq][1];
          val.z = O[f][qq][2]; val.w = O[f][qq][3];
          if (w != 0) {
            float4 old = *dst;
            val.x += old.x; val.y += old.y; val.z += old.z; val.w += old.w;
          }
          *dst = val;
        }
    }
    __syncthreads();
  }
  {
    int q = threadIdx.x >> 2, ds = (threadIdx.x & 3) << 4;
    float lst = ls[0][q] + ls[1][q] + ls[2][q] + ls[3][q];
    float invl = 1.f / lst;
    __bf16* orow = ao + ((size_t)batch*S_ + q0 + q)*D_ + h*DH_ + ds;
    v8bf o0, o1;
    #pragma unroll
    for (int i = 0; i < 8; i++) {
      o0[i] = (__bf16)(Ored[q][ds + i] * invl);
      o1[i] = (__bf16)(Ored[q][ds + 8 + i] * invl);
    }
    *(v8bf*)orow = o0;
    *(v8bf*)(orow + 8) = o1;
  }
}

// ---------------- output projection (64x64 tiles): fp32 out ----------------
__global__ __launch_bounds__(256) void out_gemm(
    const __bf16* __restrict__ Ao, const __bf16* __restrict__ Wob,
    const float* __restrict__ bo, float* __restrict__ out)
{
  __shared__ __bf16 lds[(64+64)*32];   // 8 KB
  const int m0 = blockIdx.y << 6, n0 = blockIdx.x << 6;
  v4f acc[2][2];
  #pragma unroll
  for (int i = 0; i < 2; i++)
    #pragma unroll
    for (int j = 0; j < 2; j++) { v4f z = {0.f,0.f,0.f,0.f}; acc[i][j] = z; }
  gemm_core_lds<64,64>(Ao, Wob, m0, n0, lds, acc);

  const int lane = threadIdx.x & 63;
  const int wave = threadIdx.x >> 6;
  const int wm = (wave >> 1) << 5, wn = (wave & 1) << 5;
  const int col = lane & 15, quad = lane >> 4;
  float bb[2]; int nn[2];
  #pragma unroll
  for (int j = 0; j < 2; j++) { nn[j] = n0 + wn + 16*j + col; bb[j] = bo[nn[j]]; }
  #pragma unroll
  for (int i = 0; i < 2; i++)
    #pragma unroll
    for (int r = 0; r < 4; r++) {
      int m = m0 + wm + 16*i + quad*4 + r;
      #pragma unroll
      for (int j = 0; j < 2; j++)
        out[(size_t)m*D_ + nn[j]] = acc[i][j][r] + bb[j];
    }
}

extern "C" void kernel_launch(void* const* d_in, const int* in_sizes, int n_in,
                              void* d_out, int out_size, void* d_ws, size_t ws_size,
                              hipStream_t stream)
{
  const float* q    = (const float*)d_in[0];
  const float* k    = (const float*)d_in[1];
  const float* v    = (const float*)d_in[2];
  const float* mask = (const float*)d_in[3];
  const float* Wq   = (const float*)d_in[4];
  const float* bq   = (const float*)d_in[5];
  const float* Wk   = (const float*)d_in[6];
  const float* bk   = (const float*)d_in[7];
  const float* Wv   = (const float*)d_in[8];
  const float* bv   = (const float*)d_in[9];
  const float* Wo   = (const float*)d_in[10];
  const float* bo   = (const float*)d_in[11];

  const size_t XN = (size_t)M_ * D_;
  const size_t WN = (size_t)D_ * D_;
  const size_t HN = (size_t)BH_ * S_ * DH_;

  char* ws = (char*)d_ws;
  __bf16* Xq  = (__bf16*)ws;                 ws += XN * 2;
  __bf16* Xk  = (__bf16*)ws;                 ws += XN * 2;
  __bf16* Xv  = (__bf16*)ws;                 ws += XN * 2;
  __bf16* Wqb = (__bf16*)ws;                 ws += WN * 2;
  __bf16* Wkb = (__bf16*)ws;                 ws += WN * 2;
  __bf16* Wvb = (__bf16*)ws;                 ws += WN * 2;
  __bf16* Wob = (__bf16*)ws;                 ws += WN * 2;
  __bf16* qfb = (__bf16*)ws;                 ws += HN * 2;
  __bf16* kfb = (__bf16*)ws;                 ws += HN * 2;
  __bf16* vfb = (__bf16*)ws;                 ws += HN * 2;
  __bf16* aob = (__bf16*)ws;                 ws += XN * 2;
  // em (8.4 MB) aliases Xq+Xk (12 MB) — dead after qkv_gemm; em_kernel runs after it.
  __bf16* emb = Xq;

  convert_kernel<<<dim3(3072, 7), 256, 0, stream>>>(
      q, k, v, Wq, Wk, Wv, Wo, Xq, Xk, Xv, Wqb, Wkb, Wvb, Wob);
  qkv_gemm<<<dim3(12, 32, 3), 256, 0, stream>>>(
      Xq, Xk, Xv, Wqb, Wkb, Wvb, bq, bk, bv, qfb, kfb, vfb);
  em_kernel<<<dim3(2048), 256, 0, stream>>>(mask, emb);
  attn_kernel<<<dim3(32, 24), 256, 0, stream>>>(qfb, kfb, vfb, emb, aob);
  out_gemm<<<dim3(12, 64), 256, 0, stream>>>(aob, Wob, bo, (float*)d_out);
}

// Round 2
// 259.227 us; speedup vs baseline: 1.0942x; 1.0942x over previous
//
#include <hip/hip_runtime.h>
#include <hip/hip_bf16.h>

#define B_ 2
#define S_ 2048
#define D_ 768
#define H_ 12
#define DH_ 64
#define M_ (B_*S_)     // 4096
#define BH_ (B_*H_)    // 24

typedef __bf16 v8bf __attribute__((ext_vector_type(8)));
typedef __bf16 v4bf __attribute__((ext_vector_type(4)));
typedef float  v4f  __attribute__((ext_vector_type(4)));

static __device__ __forceinline__ v4f mfma16(v8bf a, v8bf b, v4f c) {
  return __builtin_amdgcn_mfma_f32_16x16x32_bf16(a, b, c, 0, 0, 0);
}

// async global->LDS, 16 B/lane; dest = wave-uniform base + lane*16
static __device__ __forceinline__ void gload_lds16(const __bf16* g, __bf16* l) {
  __builtin_amdgcn_global_load_lds(
      (const __attribute__((address_space(1))) unsigned int*)g,
      (__attribute__((address_space(3))) unsigned int*)l,
      16, 0, 0);
}

#define C1_ 0.18033688011112042f   // log2(e)/sqrt(DH)

// ---------------- fp32 -> bf16 conversion ----------------
__global__ __launch_bounds__(256) void convert_kernel(
    const float* __restrict__ q, const float* __restrict__ k, const float* __restrict__ v,
    const float* __restrict__ Wq, const float* __restrict__ Wk,
    const float* __restrict__ Wv, const float* __restrict__ Wo,
    __bf16* __restrict__ Xq, __bf16* __restrict__ Xk, __bf16* __restrict__ Xv,
    __bf16* __restrict__ Wqb, __bf16* __restrict__ Wkb,
    __bf16* __restrict__ Wvb, __bf16* __restrict__ Wob)
{
  const float* src; __bf16* dst; int n;
  switch (blockIdx.y) {
    case 0: src = q;  dst = Xq;  n = M_*D_; break;
    case 1: src = k;  dst = Xk;  n = M_*D_; break;
    case 2: src = v;  dst = Xv;  n = M_*D_; break;
    case 3: src = Wq; dst = Wqb; n = D_*D_; break;
    case 4: src = Wk; dst = Wkb; n = D_*D_; break;
    case 5: src = Wv; dst = Wvb; n = D_*D_; break;
    default: src = Wo; dst = Wob; n = D_*D_; break;
  }
  int n4 = n >> 2;
  for (int i = blockIdx.x*blockDim.x + threadIdx.x; i < n4; i += gridDim.x*blockDim.x) {
    float4 x = ((const float4*)src)[i];
    v4bf y;
    y[0] = (__bf16)x.x; y[1] = (__bf16)x.y; y[2] = (__bf16)x.z; y[3] = (__bf16)x.w;
    ((v4bf*)dst)[i] = y;
  }
}

// ---------------- em precompute: em = bf16(exp2(C1*mask)) in attn-lane order ----------------
// flat t = (((qt*64 + kt)*8 + w)*64 + L); elem t*8 + (krow*4 + r) holds
// exp2(C1*mask[qt*128 + w*16 + (L&15)][kt*32 + krow*16 + (L>>4)*4 + r]).
__global__ __launch_bounds__(256) void em_kernel(
    const float* __restrict__ mask, __bf16* __restrict__ em)
{
  int t = blockIdx.x*256 + threadIdx.x;        // 0 .. 524287
  int L = t & 63; int rest = t >> 6;
  int w = rest & 7; rest >>= 3;
  int kt = rest & 63; rest >>= 6;
  int qt = rest;                                // 0..15
  int row = qt*128 + w*16 + (L & 15);
  int key0 = kt*32 + ((L >> 4) << 2);
  const float* mp = mask + (size_t)row*S_ + key0;
  float4 m0 = *(const float4*)mp;
  float4 m1 = *(const float4*)(mp + 16);
  v8bf e;
  e[0] = (__bf16)exp2f(C1_*m0.x); e[1] = (__bf16)exp2f(C1_*m0.y);
  e[2] = (__bf16)exp2f(C1_*m0.z); e[3] = (__bf16)exp2f(C1_*m0.w);
  e[4] = (__bf16)exp2f(C1_*m1.x); e[5] = (__bf16)exp2f(C1_*m1.y);
  e[6] = (__bf16)exp2f(C1_*m1.z); e[7] = (__bf16)exp2f(C1_*m1.w);
  *(v8bf*)(em + (size_t)t*8) = e;
}

// ---------------- templated LDS-staged NT-GEMM core: C[BMxBN] = A @ W^T ----------------
template<int BM, int BN>
static __device__ __forceinline__ void gemm_core_lds(
    const __bf16* __restrict__ A, const __bf16* __restrict__ W,
    int m0, int n0, __bf16* lds, v4f acc[BM/32][BN/32])
{
  constexpr int NFA = BM/16, NFB = BN/16;
  constexpr int PW  = (NFA + NFB) / 4;
  constexpr int MI  = BM/32, NJ = BN/32;
  const int lane = threadIdx.x & 63;
  const int wave = threadIdx.x >> 6;
  const int r16 = lane & 15;
  const int kc8 = (lane >> 4) << 3;
  const int ia = (wave >> 1) * MI;
  const int ib = (wave & 1) * NJ;

  const __bf16* gsrc[PW]; __bf16* ldst[PW];
  #pragma unroll
  for (int t = 0; t < PW; t++) {
    int fb = wave*PW + t;
    gsrc[t] = (fb < NFA)
        ? A + (size_t)(m0 + fb*16 + r16)*D_ + kc8
        : W + (size_t)(n0 + (fb - NFA)*16 + r16)*D_ + kc8;
    ldst[t] = lds + fb*512;
  }

  for (int k0 = 0; k0 < D_; k0 += 32) {
    #pragma unroll
    for (int t = 0; t < PW; t++) gload_lds16(gsrc[t] + k0, ldst[t]);
    __syncthreads();
    v8bf a[MI], b[NJ];
    #pragma unroll
    for (int i = 0; i < MI; i++) a[i] = *(const v8bf*)(lds + (ia+i)*512 + lane*8);
    #pragma unroll
    for (int j = 0; j < NJ; j++) b[j] = *(const v8bf*)(lds + (NFA+ib+j)*512 + lane*8);
    #pragma unroll
    for (int i = 0; i < MI; i++)
      #pragma unroll
      for (int j = 0; j < NJ; j++)
        acc[i][j] = mfma16(a[i], b[j], acc[i][j]);
    __syncthreads();
  }
}

// ---------------- QKV projection (128x64 tiles) -> FRAGMENT-ORDERED qf/kf/vf ----------------
// qf/kf: per bh, per s16-block, per half: 512 elems; elem[lane*8+j] =
//   X[s16*16+(lane&15)][half*32+(lane>>4)*8+j].   (B-op for Q, A-op for K: same formula)
// qf additionally carries the C1 = log2(e)/sqrt(DH) scale (folded in fp32 before bf16 round).
// vf: per bh, per ktile32, per f: 512 elems; elem[lane*8+j] =
//   V[ktile*32+(lane>>4)*8+j][f*16+(lane&15)].
__global__ __launch_bounds__(256) void qkv_gemm(
    const __bf16* __restrict__ Xq, const __bf16* __restrict__ Xk, const __bf16* __restrict__ Xv,
    const __bf16* __restrict__ Wqb, const __bf16* __restrict__ Wkb, const __bf16* __restrict__ Wvb,
    const float* __restrict__ bq, const float* __restrict__ bk, const float* __restrict__ bv,
    __bf16* __restrict__ qf, __bf16* __restrict__ kf, __bf16* __restrict__ vf)
{
  __shared__ __bf16 lds[(128+64)*32];   // 12 KB
  const int mode = blockIdx.z;
  const __bf16* A = (mode == 0) ? Xq : (mode == 1) ? Xk : Xv;
  const __bf16* W = (mode == 0) ? Wqb : (mode == 1) ? Wkb : Wvb;
  const float* bias = (mode == 0) ? bq : (mode == 1) ? bk : bv;
  const int m0 = blockIdx.y << 7, n0 = blockIdx.x << 6;
  v4f acc[4][2];
  #pragma unroll
  for (int i = 0; i < 4; i++)
    #pragma unroll
    for (int j = 0; j < 2; j++) { v4f z = {0.f,0.f,0.f,0.f}; acc[i][j] = z; }
  gemm_core_lds<128,64>(A, W, m0, n0, lds, acc);

  const int lane = threadIdx.x & 63;
  const int wave = threadIdx.x >> 6;
  const int wm = (wave >> 1) << 6, wn = (wave & 1) << 5;
  const int col = lane & 15, quad = lane >> 4;
  float bb[2]; int nn[2];
  #pragma unroll
  for (int j = 0; j < 2; j++) { nn[j] = n0 + wn + 16*j + col; bb[j] = bias[nn[j]]; }

  if (mode < 2) {
    __bf16* dst = (mode == 0) ? qf : kf;
    const float sc = (mode == 0) ? C1_ : 1.0f;
    #pragma unroll
    for (int i = 0; i < 4; i++)
      #pragma unroll
      for (int r = 0; r < 4; r++) {
        int m = m0 + wm + 16*i + quad*4 + r;
        int batch = m >> 11, s = m & (S_-1);
        #pragma unroll
        for (int j = 0; j < 2; j++) {
          int n = nn[j];
          int h = n >> 6, dd = n & 63;
          size_t flat = (((size_t)(batch*H_ + h)*128 + (s >> 4))*2 + (dd >> 5))*512
                      + ((((dd >> 3) & 3)*16 + (s & 15)) << 3) + (dd & 7);
          dst[flat] = (__bf16)((acc[i][j][r] + bb[j]) * sc);
        }
      }
  } else {
    #pragma unroll
    for (int i = 0; i < 4; i++) {
      int mbase = m0 + wm + 16*i + quad*4;
      int batch = mbase >> 11, s0 = mbase & (S_-1);
      #pragma unroll
      for (int j = 0; j < 2; j++) {
        int n = nn[j];
        int h = n >> 6, dd = n & 63;
        v4bf pk;
        #pragma unroll
        for (int r = 0; r < 4; r++) pk[r] = (__bf16)(acc[i][j][r] + bb[j]);
        size_t flat = (((size_t)(batch*H_ + h)*64 + (s0 >> 5))*4 + (dd >> 4))*512
                    + ((((s0 >> 3) & 3)*16 + (dd & 15)) << 3) + (s0 & 7);
        *(v4bf*)(vf + flat) = pk;
      }
    }
  }
}

// ---------------- flash attention: 128 q/block, 8 waves, LDS-shared K/V ----------------
// Each wave owns 16 queries and walks all 2048 keys in 64 steps of 32.  K/V tiles
// (4 KB each) are staged ONCE per block into double-buffered LDS via global_load_lds
// (waves 0-3 stage K, 4-7 stage V: exactly 16 B x 512 lanes per step) and shared by
// all 8 waves -> K/V L3 re-read factor drops 32x -> 16x vs the 64q split-K version,
// and the split-K combine epilogue disappears.  One __syncthreads per step (its
// vmcnt drain covers the next tile's in-flight stage).  em stays L2-resident
// (grid x%8 XCD mapping, 1 MB/XCD).
__global__ __launch_bounds__(512, 4) void attn_kernel(
    const __bf16* __restrict__ qf, const __bf16* __restrict__ kf, const __bf16* __restrict__ vf,
    const __bf16* __restrict__ em, __bf16* __restrict__ ao)
{
  __shared__ __bf16 kv[2][2][2048];   // [buf][K=0/V=1][32 keys x 64 dh]  16 KB
  __shared__ __bf16 plds[8][16][40];  // per-wave P transpose, padded     10 KB

  const int bh = blockIdx.y;
  const int qt = blockIdx.x;                     // 0..15  (128-query tile)
  const int wave = threadIdx.x >> 6, lane = threadIdx.x & 63;
  const int col = lane & 15, quad = lane >> 4, koff = quad << 3;
  const int batch = bh / H_, h = bh % H_;
  const __bf16* qfb = qf + (size_t)bh * (S_*DH_);
  const __bf16* kfb = kf + (size_t)bh * (S_*DH_);
  const __bf16* vfb = vf + (size_t)bh * (S_*DH_);
  const __bf16* emb = em + (size_t)qt * 262144 + wave*512;  // + kt*4096 per step
  __bf16 (*pt)[40] = plds[wave];

  // Q fragments for this wave's 16 queries (s16 block = qt*8 + wave)
  const __bf16* qblk = qfb + (size_t)(qt*8 + wave)*1024;
  v8bf Qf0 = *(const v8bf*)(qblk + lane*8);
  v8bf Qf1 = *(const v8bf*)(qblk + 512 + lane*8);

  v4f O[4];
  #pragma unroll
  for (int f = 0; f < 4; f++) { v4f z = {0.f,0.f,0.f,0.f}; O[f] = z; }
  float li = 0.f;

  // staging assignment: waves 0-3 -> K slice, waves 4-7 -> V slice (512 elems each)
  const __bf16* gsrc = ((wave < 4) ? kfb : vfb) + ((wave & 3) << 9) + lane*8;
  __bf16* ld0 = &kv[0][wave >> 2][(wave & 3) << 9];
  __bf16* ld1 = &kv[1][wave >> 2][(wave & 3) << 9];

  // prologue: stage tile 0 into buf 0
  gload_lds16(gsrc, ld0);
  __syncthreads();

  #pragma unroll 2
  for (int kt = 0; kt < 64; kt++) {
    const int buf = kt & 1;
    if (kt + 1 < 64)
      gload_lds16(gsrc + (size_t)(kt + 1)*2048, buf ? ld0 : ld1);

    const __bf16* Kb = kv[buf][0];
    const __bf16* Vb = kv[buf][1];

    v8bf ef = *(const v8bf*)(emb + kt*4096 + lane*8);   // L2-resident
    v8bf Vf0 = *(const v8bf*)(Vb + lane*8);
    v8bf Vf1 = *(const v8bf*)(Vb + 512 + lane*8);
    v8bf Vf2 = *(const v8bf*)(Vb + 1024 + lane*8);
    v8bf Vf3 = *(const v8bf*)(Vb + 1536 + lane*8);
    v8bf Ka0 = *(const v8bf*)(Kb + lane*8);
    v8bf Ka1 = *(const v8bf*)(Kb + 512 + lane*8);
    v8bf Ka2 = *(const v8bf*)(Kb + 1024 + lane*8);
    v8bf Ka3 = *(const v8bf*)(Kb + 1536 + lane*8);

    v4f s0 = {0.f,0.f,0.f,0.f}, s1 = {0.f,0.f,0.f,0.f};
    s0 = mfma16(Ka0, Qf0, s0); s0 = mfma16(Ka1, Qf1, s0);
    s1 = mfma16(Ka2, Qf0, s1); s1 = mfma16(Ka3, Qf1, s1);

    float p[8], rs = 0.f;
    #pragma unroll
    for (int j = 0; j < 4; j++) {
      p[j]   = exp2f(s0[j]) * (float)ef[j];
      p[4+j] = exp2f(s1[j]) * (float)ef[4+j];
    }
    #pragma unroll
    for (int j = 0; j < 8; j++) rs += p[j];
    li += rs;

    v4bf pk0, pk1;
    #pragma unroll
    for (int r = 0; r < 4; r++) { pk0[r] = (__bf16)p[r]; pk1[r] = (__bf16)p[4+r]; }
    *(v4bf*)(&pt[col][quad*4])      = pk0;
    *(v4bf*)(&pt[col][16 + quad*4]) = pk1;
    v8bf Pf = *(const v8bf*)(&pt[col][koff]);   // within-wave RAW (lgkmcnt)

    O[0] = mfma16(Vf0, Pf, O[0]);
    O[1] = mfma16(Vf1, Pf, O[1]);
    O[2] = mfma16(Vf2, Pf, O[2]);
    O[3] = mfma16(Vf3, Pf, O[3]);

    __syncthreads();   // drains the in-flight stage of tile kt+1, flips buffer
  }

  // ---- epilogue: per-wave complete rows, no split-K combine ----
  float rs = li;
  rs += __shfl_xor(rs, 16);
  rs += __shfl_xor(rs, 32);
  float invl = 1.f / rs;
  const int qg = (qt << 7) + (wave << 4) + col;
  __bf16* orow = ao + ((size_t)batch*S_ + qg)*D_ + h*DH_ + quad*4;
  #pragma unroll
  for (int f = 0; f < 4; f++) {
    v4bf o;
    #pragma unroll
    for (int r = 0; r < 4; r++) o[r] = (__bf16)(O[f][r] * invl);
    *(v4bf*)(orow + f*16) = o;
  }
}

// ---------------- output projection (64x64 tiles): fp32 out ----------------
__global__ __launch_bounds__(256) void out_gemm(
    const __bf16* __restrict__ Ao, const __bf16* __restrict__ Wob,
    const float* __restrict__ bo, float* __restrict__ out)
{
  __shared__ __bf16 lds[(64+64)*32];   // 8 KB
  const int m0 = blockIdx.y << 6, n0 = blockIdx.x << 6;
  v4f acc[2][2];
  #pragma unroll
  for (int i = 0; i < 2; i++)
    #pragma unroll
    for (int j = 0; j < 2; j++) { v4f z = {0.f,0.f,0.f,0.f}; acc[i][j] = z; }
  gemm_core_lds<64,64>(Ao, Wob, m0, n0, lds, acc);

  const int lane = threadIdx.x & 63;
  const int wave = threadIdx.x >> 6;
  const int wm = (wave >> 1) << 5, wn = (wave & 1) << 5;
  const int col = lane & 15, quad = lane >> 4;
  float bb[2]; int nn[2];
  #pragma unroll
  for (int j = 0; j < 2; j++) { nn[j] = n0 + wn + 16*j + col; bb[j] = bo[nn[j]]; }
  #pragma unroll
  for (int i = 0; i < 2; i++)
    #pragma unroll
    for (int r = 0; r < 4; r++) {
      int m = m0 + wm + 16*i + quad*4 + r;
      #pragma unroll
      for (int j = 0; j < 2; j++)
        out[(size_t)m*D_ + nn[j]] = acc[i][j][r] + bb[j];
    }
}

extern "C" void kernel_launch(void* const* d_in, const int* in_sizes, int n_in,
                              void* d_out, int out_size, void* d_ws, size_t ws_size,
                              hipStream_t stream)
{
  const float* q    = (const float*)d_in[0];
  const float* k    = (const float*)d_in[1];
  const float* v    = (const float*)d_in[2];
  const float* mask = (const float*)d_in[3];
  const float* Wq   = (const float*)d_in[4];
  const float* bq   = (const float*)d_in[5];
  const float* Wk   = (const float*)d_in[6];
  const float* bk   = (const float*)d_in[7];
  const float* Wv   = (const float*)d_in[8];
  const float* bv   = (const float*)d_in[9];
  const float* Wo   = (const float*)d_in[10];
  const float* bo   = (const float*)d_in[11];

  const size_t XN = (size_t)M_ * D_;
  const size_t WN = (size_t)D_ * D_;
  const size_t HN = (size_t)BH_ * S_ * DH_;

  char* ws = (char*)d_ws;
  __bf16* Xq  = (__bf16*)ws;                 ws += XN * 2;
  __bf16* Xk  = (__bf16*)ws;                 ws += XN * 2;
  __bf16* Xv  = (__bf16*)ws;                 ws += XN * 2;
  __bf16* Wqb = (__bf16*)ws;                 ws += WN * 2;
  __bf16* Wkb = (__bf16*)ws;                 ws += WN * 2;
  __bf16* Wvb = (__bf16*)ws;                 ws += WN * 2;
  __bf16* Wob = (__bf16*)ws;                 ws += WN * 2;
  __bf16* qfb = (__bf16*)ws;                 ws += HN * 2;
  __bf16* kfb = (__bf16*)ws;                 ws += HN * 2;
  __bf16* vfb = (__bf16*)ws;                 ws += HN * 2;
  __bf16* aob = (__bf16*)ws;                 ws += XN * 2;
  // em (8.4 MB) aliases Xq+Xk (12 MB) — dead after qkv_gemm; em_kernel runs after it.
  __bf16* emb = Xq;

  convert_kernel<<<dim3(3072, 7), 256, 0, stream>>>(
      q, k, v, Wq, Wk, Wv, Wo, Xq, Xk, Xv, Wqb, Wkb, Wvb, Wob);
  qkv_gemm<<<dim3(12, 32, 3), 256, 0, stream>>>(
      Xq, Xk, Xv, Wqb, Wkb, Wvb, bq, bk, bv, qfb, kfb, vfb);
  em_kernel<<<dim3(2048), 256, 0, stream>>>(mask, emb);
  attn_kernel<<<dim3(16, 24), 512, 0, stream>>>(qfb, kfb, vfb, emb, aob);
  out_gemm<<<dim3(12, 64), 256, 0, stream>>>(aob, Wob, bo, (float*)d_out);
}

// Round 3
// 253.141 us; speedup vs baseline: 1.1205x; 1.0240x over previous
//
#include <hip/hip_runtime.h>
#include <hip/hip_bf16.h>

#define B_ 2
#define S_ 2048
#define D_ 768
#define H_ 12
#define DH_ 64
#define M_ (B_*S_)     // 4096
#define BH_ (B_*H_)    // 24

typedef __bf16 v8bf __attribute__((ext_vector_type(8)));
typedef __bf16 v4bf __attribute__((ext_vector_type(4)));
typedef float  v4f  __attribute__((ext_vector_type(4)));

static __device__ __forceinline__ v4f mfma16(v8bf a, v8bf b, v4f c) {
  return __builtin_amdgcn_mfma_f32_16x16x32_bf16(a, b, c, 0, 0, 0);
}

// async global->LDS, 16 B/lane; dest = wave-uniform base + lane*16
static __device__ __forceinline__ void gload_lds16(const __bf16* g, __bf16* l) {
  __builtin_amdgcn_global_load_lds(
      (const __attribute__((address_space(1))) unsigned int*)g,
      (__attribute__((address_space(3))) unsigned int*)l,
      16, 0, 0);
}

#define C1_ 0.18033688011112042f   // log2(e)/sqrt(DH)

// ---------------- fp32 -> bf16 conversion ----------------
__global__ __launch_bounds__(256) void convert_kernel(
    const float* __restrict__ q, const float* __restrict__ k, const float* __restrict__ v,
    const float* __restrict__ Wq, const float* __restrict__ Wk,
    const float* __restrict__ Wv, const float* __restrict__ Wo,
    __bf16* __restrict__ Xq, __bf16* __restrict__ Xk, __bf16* __restrict__ Xv,
    __bf16* __restrict__ Wqb, __bf16* __restrict__ Wkb,
    __bf16* __restrict__ Wvb, __bf16* __restrict__ Wob)
{
  const float* src; __bf16* dst; int n;
  switch (blockIdx.y) {
    case 0: src = q;  dst = Xq;  n = M_*D_; break;
    case 1: src = k;  dst = Xk;  n = M_*D_; break;
    case 2: src = v;  dst = Xv;  n = M_*D_; break;
    case 3: src = Wq; dst = Wqb; n = D_*D_; break;
    case 4: src = Wk; dst = Wkb; n = D_*D_; break;
    case 5: src = Wv; dst = Wvb; n = D_*D_; break;
    default: src = Wo; dst = Wob; n = D_*D_; break;
  }
  int n4 = n >> 2;
  for (int i = blockIdx.x*blockDim.x + threadIdx.x; i < n4; i += gridDim.x*blockDim.x) {
    float4 x = ((const float4*)src)[i];
    v4bf y;
    y[0] = (__bf16)x.x; y[1] = (__bf16)x.y; y[2] = (__bf16)x.z; y[3] = (__bf16)x.w;
    ((v4bf*)dst)[i] = y;
  }
}

// ---------------- em precompute: em = bf16(exp2(C1*mask)) in attn-lane order ----------------
// flat t = (((qt*64 + kt)*8 + w)*64 + L); elem t*8 + (krow*4 + r) holds
// exp2(C1*mask[qt*128 + w*16 + (L&15)][kt*32 + krow*16 + (L>>4)*4 + r]).
__global__ __launch_bounds__(256) void em_kernel(
    const float* __restrict__ mask, __bf16* __restrict__ em)
{
  int t = blockIdx.x*256 + threadIdx.x;        // 0 .. 524287
  int L = t & 63; int rest = t >> 6;
  int w = rest & 7; rest >>= 3;
  int kt = rest & 63; rest >>= 6;
  int qt = rest;                                // 0..15
  int row = qt*128 + w*16 + (L & 15);
  int key0 = kt*32 + ((L >> 4) << 2);
  const float* mp = mask + (size_t)row*S_ + key0;
  float4 m0 = *(const float4*)mp;
  float4 m1 = *(const float4*)(mp + 16);
  v8bf e;
  e[0] = (__bf16)exp2f(C1_*m0.x); e[1] = (__bf16)exp2f(C1_*m0.y);
  e[2] = (__bf16)exp2f(C1_*m0.z); e[3] = (__bf16)exp2f(C1_*m0.w);
  e[4] = (__bf16)exp2f(C1_*m1.x); e[5] = (__bf16)exp2f(C1_*m1.y);
  e[6] = (__bf16)exp2f(C1_*m1.z); e[7] = (__bf16)exp2f(C1_*m1.w);
  *(v8bf*)(em + (size_t)t*8) = e;
}

// ---------------- templated LDS-staged NT-GEMM core: C[BMxBN] = A @ W^T ----------------
template<int BM, int BN>
static __device__ __forceinline__ void gemm_core_lds(
    const __bf16* __restrict__ A, const __bf16* __restrict__ W,
    int m0, int n0, __bf16* lds, v4f acc[BM/32][BN/32])
{
  constexpr int NFA = BM/16, NFB = BN/16;
  constexpr int PW  = (NFA + NFB) / 4;
  constexpr int MI  = BM/32, NJ = BN/32;
  const int lane = threadIdx.x & 63;
  const int wave = threadIdx.x >> 6;
  const int r16 = lane & 15;
  const int kc8 = (lane >> 4) << 3;
  const int ia = (wave >> 1) * MI;
  const int ib = (wave & 1) * NJ;

  const __bf16* gsrc[PW]; __bf16* ldst[PW];
  #pragma unroll
  for (int t = 0; t < PW; t++) {
    int fb = wave*PW + t;
    gsrc[t] = (fb < NFA)
        ? A + (size_t)(m0 + fb*16 + r16)*D_ + kc8
        : W + (size_t)(n0 + (fb - NFA)*16 + r16)*D_ + kc8;
    ldst[t] = lds + fb*512;
  }

  for (int k0 = 0; k0 < D_; k0 += 32) {
    #pragma unroll
    for (int t = 0; t < PW; t++) gload_lds16(gsrc[t] + k0, ldst[t]);
    __syncthreads();
    v8bf a[MI], b[NJ];
    #pragma unroll
    for (int i = 0; i < MI; i++) a[i] = *(const v8bf*)(lds + (ia+i)*512 + lane*8);
    #pragma unroll
    for (int j = 0; j < NJ; j++) b[j] = *(const v8bf*)(lds + (NFA+ib+j)*512 + lane*8);
    #pragma unroll
    for (int i = 0; i < MI; i++)
      #pragma unroll
      for (int j = 0; j < NJ; j++)
        acc[i][j] = mfma16(a[i], b[j], acc[i][j]);
    __syncthreads();
  }
}

// ---------------- QKV projection (128x64 tiles) -> FRAGMENT-ORDERED qf/kf/vf ----------------
__global__ __launch_bounds__(256) void qkv_gemm(
    const __bf16* __restrict__ Xq, const __bf16* __restrict__ Xk, const __bf16* __restrict__ Xv,
    const __bf16* __restrict__ Wqb, const __bf16* __restrict__ Wkb, const __bf16* __restrict__ Wvb,
    const float* __restrict__ bq, const float* __restrict__ bk, const float* __restrict__ bv,
    __bf16* __restrict__ qf, __bf16* __restrict__ kf, __bf16* __restrict__ vf)
{
  __shared__ __bf16 lds[(128+64)*32];   // 12 KB
  const int mode = blockIdx.z;
  const __bf16* A = (mode == 0) ? Xq : (mode == 1) ? Xk : Xv;
  const __bf16* W = (mode == 0) ? Wqb : (mode == 1) ? Wkb : Wvb;
  const float* bias = (mode == 0) ? bq : (mode == 1) ? bk : bv;
  const int m0 = blockIdx.y << 7, n0 = blockIdx.x << 6;
  v4f acc[4][2];
  #pragma unroll
  for (int i = 0; i < 4; i++)
    #pragma unroll
    for (int j = 0; j < 2; j++) { v4f z = {0.f,0.f,0.f,0.f}; acc[i][j] = z; }
  gemm_core_lds<128,64>(A, W, m0, n0, lds, acc);

  const int lane = threadIdx.x & 63;
  const int wave = threadIdx.x >> 6;
  const int wm = (wave >> 1) << 6, wn = (wave & 1) << 5;
  const int col = lane & 15, quad = lane >> 4;
  float bb[2]; int nn[2];
  #pragma unroll
  for (int j = 0; j < 2; j++) { nn[j] = n0 + wn + 16*j + col; bb[j] = bias[nn[j]]; }

  if (mode < 2) {
    __bf16* dst = (mode == 0) ? qf : kf;
    const float sc = (mode == 0) ? C1_ : 1.0f;
    #pragma unroll
    for (int i = 0; i < 4; i++)
      #pragma unroll
      for (int r = 0; r < 4; r++) {
        int m = m0 + wm + 16*i + quad*4 + r;
        int batch = m >> 11, s = m & (S_-1);
        #pragma unroll
        for (int j = 0; j < 2; j++) {
          int n = nn[j];
          int h = n >> 6, dd = n & 63;
          size_t flat = (((size_t)(batch*H_ + h)*128 + (s >> 4))*2 + (dd >> 5))*512
                      + ((((dd >> 3) & 3)*16 + (s & 15)) << 3) + (dd & 7);
          dst[flat] = (__bf16)((acc[i][j][r] + bb[j]) * sc);
        }
      }
  } else {
    #pragma unroll
    for (int i = 0; i < 4; i++) {
      int mbase = m0 + wm + 16*i + quad*4;
      int batch = mbase >> 11, s0 = mbase & (S_-1);
      #pragma unroll
      for (int j = 0; j < 2; j++) {
        int n = nn[j];
        int h = n >> 6, dd = n & 63;
        v4bf pk;
        #pragma unroll
        for (int r = 0; r < 4; r++) pk[r] = (__bf16)(acc[i][j][r] + bb[j]);
        size_t flat = (((size_t)(batch*H_ + h)*64 + (s0 >> 5))*4 + (dd >> 4))*512
                    + ((((s0 >> 3) & 3)*16 + (dd & 15)) << 3) + (s0 & 7);
        *(v4bf*)(vf + flat) = pk;
      }
    }
  }
}

// ---------------- flash attention: 128 q/block, 8 waves, LDS-shared K/V ----------------
// Counted-vmcnt pipeline (T3/T4): 4 LDS K/V buffers, 2 tiles of lookahead.  Per step each
// lane issues EXACTLY 2 VMEM ops for tile kt+2 (1 global_load_lds of its K-or-V slice +
// 1 em global load into rotating regs ef0..ef3).  Top of each step: s_waitcnt vmcnt(2)
// (waits only tile kt's pair, in-order retirement; tile kt+1's pair stays in flight
// ACROSS the raw s_barrier) -> the stage latency has ~2 full steps to complete instead
// of <1 step with __syncthreads' vmcnt(0) drain.  Buffer (kt+2)&3 is safe to overwrite:
// passing barrier kt proves every wave finished reading it at step kt-2.
__global__ __launch_bounds__(512, 2) void attn_kernel(
    const __bf16* __restrict__ qf, const __bf16* __restrict__ kf, const __bf16* __restrict__ vf,
    const __bf16* __restrict__ em, __bf16* __restrict__ ao)
{
  __shared__ __bf16 kv[4][2][2048];   // [buf][K=0/V=1][32 keys x 64 dh]  32 KB
  __shared__ __bf16 plds[8][16][40];  // per-wave P transpose, padded     10 KB

  const int bh = blockIdx.y;
  const int qt = blockIdx.x;                     // 0..15  (128-query tile)
  const int wave = threadIdx.x >> 6, lane = threadIdx.x & 63;
  const int col = lane & 15, quad = lane >> 4, koff = quad << 3;
  const int batch = bh / H_, h = bh % H_;
  const __bf16* qfb = qf + (size_t)bh * (S_*DH_);
  const __bf16* kfb = kf + (size_t)bh * (S_*DH_);
  const __bf16* vfb = vf + (size_t)bh * (S_*DH_);
  const __bf16* emw = em + (size_t)qt * 262144 + wave*512 + lane*8;  // + kt*4096 per step
  __bf16 (*pt)[40] = plds[wave];

  // staging assignment: waves 0-3 -> K slice, waves 4-7 -> V slice (512 elems each)
  const __bf16* gsrc = ((wave < 4) ? kfb : vfb) + ((wave & 3) << 9) + lane*8;
  __bf16* kvd[4];
  #pragma unroll
  for (int b = 0; b < 4; b++) kvd[b] = &kv[b][wave >> 2][(wave & 3) << 9];

  // Q fragments for this wave's 16 queries (s16 block = qt*8 + wave)
  const __bf16* qblk = qfb + (size_t)(qt*8 + wave)*1024;
  v8bf Qf0 = *(const v8bf*)(qblk + lane*8);
  v8bf Qf1 = *(const v8bf*)(qblk + 512 + lane*8);

  v4f O[4];
  #pragma unroll
  for (int f = 0; f < 4; f++) { v4f z = {0.f,0.f,0.f,0.f}; O[f] = z; }
  float li = 0.f;

  // ---- pipelined prologue: stage tiles 0 and 1, em regs 0 and 1 (order pinned) ----
  asm volatile("" ::: "memory");
  gload_lds16(gsrc, kvd[0]);
  v8bf ef0 = *(const v8bf*)(emw);
  asm volatile("" ::: "memory");
  gload_lds16(gsrc + 2048, kvd[1]);
  v8bf ef1 = *(const v8bf*)(emw + 4096);
  v8bf ef2, ef3;

#define ATT_STEP(P, EFC, EFN, ISSUE, WSTR) \
  { \
    asm volatile("s_waitcnt vmcnt(" WSTR ")" ::: "memory"); \
    __builtin_amdgcn_s_barrier(); \
    asm volatile("" ::: "memory"); \
    if (ISSUE) { \
      const int nkt = kt0 + (P) + 2; \
      gload_lds16(gsrc + (size_t)nkt*2048, kvd[((P)+2)&3]); \
      EFN = *(const v8bf*)(emw + (size_t)nkt*4096); \
    } \
    const __bf16* Kb = kv[(P)&3][0]; \
    const __bf16* Vb = kv[(P)&3][1]; \
    v8bf Ka0 = *(const v8bf*)(Kb + lane*8); \
    v8bf Ka1 = *(const v8bf*)(Kb + 512 + lane*8); \
    v8bf Ka2 = *(const v8bf*)(Kb + 1024 + lane*8); \
    v8bf Ka3 = *(const v8bf*)(Kb + 1536 + lane*8); \
    v4f s0 = {0.f,0.f,0.f,0.f}, s1 = {0.f,0.f,0.f,0.f}; \
    s0 = mfma16(Ka0, Qf0, s0); s0 = mfma16(Ka1, Qf1, s0); \
    s1 = mfma16(Ka2, Qf0, s1); s1 = mfma16(Ka3, Qf1, s1); \
    float p[8], rs = 0.f; \
    _Pragma("unroll") \
    for (int j = 0; j < 4; j++) { \
      p[j]   = exp2f(s0[j]) * (float)EFC[j]; \
      p[4+j] = exp2f(s1[j]) * (float)EFC[4+j]; \
    } \
    _Pragma("unroll") \
    for (int j = 0; j < 8; j++) rs += p[j]; \
    li += rs; \
    v4bf pk0, pk1; \
    _Pragma("unroll") \
    for (int r = 0; r < 4; r++) { pk0[r] = (__bf16)p[r]; pk1[r] = (__bf16)p[4+r]; } \
    *(v4bf*)(&pt[col][quad*4])      = pk0; \
    *(v4bf*)(&pt[col][16 + quad*4]) = pk1; \
    v8bf Pf = *(const v8bf*)(&pt[col][koff]); \
    v8bf Vf0 = *(const v8bf*)(Vb + lane*8); \
    v8bf Vf1 = *(const v8bf*)(Vb + 512 + lane*8); \
    v8bf Vf2 = *(const v8bf*)(Vb + 1024 + lane*8); \
    v8bf Vf3 = *(const v8bf*)(Vb + 1536 + lane*8); \
    O[0] = mfma16(Vf0, Pf, O[0]); \
    O[1] = mfma16(Vf1, Pf, O[1]); \
    O[2] = mfma16(Vf2, Pf, O[2]); \
    O[3] = mfma16(Vf3, Pf, O[3]); \
  }

  #pragma unroll 1
  for (int kt0 = 0; kt0 < 60; kt0 += 4) {
    ATT_STEP(0, ef0, ef2, true, "2");
    ATT_STEP(1, ef1, ef3, true, "2");
    ATT_STEP(2, ef2, ef0, true, "2");
    ATT_STEP(3, ef3, ef1, true, "2");
  }
  {
    const int kt0 = 60;
    ATT_STEP(0, ef0, ef2, true,  "2");   // kt=60, issues pair 62
    ATT_STEP(1, ef1, ef3, true,  "2");   // kt=61, issues pair 63
    ATT_STEP(2, ef2, ef0, false, "2");   // kt=62: outstanding {62,63} -> wait leaves 63
    ATT_STEP(3, ef3, ef1, false, "0");   // kt=63: drain
  }
#undef ATT_STEP

  // ---- epilogue: per-wave complete rows ----
  float rs = li;
  rs += __shfl_xor(rs, 16);
  rs += __shfl_xor(rs, 32);
  float invl = 1.f / rs;
  const int qg = (qt << 7) + (wave << 4) + col;
  __bf16* orow = ao + ((size_t)batch*S_ + qg)*D_ + h*DH_ + quad*4;
  #pragma unroll
  for (int f = 0; f < 4; f++) {
    v4bf o;
    #pragma unroll
    for (int r = 0; r < 4; r++) o[r] = (__bf16)(O[f][r] * invl);
    *(v4bf*)(orow + f*16) = o;
  }
}

// ---------------- output projection (64x64 tiles): fp32 out ----------------
__global__ __launch_bounds__(256) void out_gemm(
    const __bf16* __restrict__ Ao, const __bf16* __restrict__ Wob,
    const float* __restrict__ bo, float* __restrict__ out)
{
  __shared__ __bf16 lds[(64+64)*32];   // 8 KB
  const int m0 = blockIdx.y << 6, n0 = blockIdx.x << 6;
  v4f acc[2][2];
  #pragma unroll
  for (int i = 0; i < 2; i++)
    #pragma unroll
    for (int j = 0; j < 2; j++) { v4f z = {0.f,0.f,0.f,0.f}; acc[i][j] = z; }
  gemm_core_lds<64,64>(Ao, Wob, m0, n0, lds, acc);

  const int lane = threadIdx.x & 63;
  const int wave = threadIdx.x >> 6;
  const int wm = (wave >> 1) << 5, wn = (wave & 1) << 5;
  const int col = lane & 15, quad = lane >> 4;
  float bb[2]; int nn[2];
  #pragma unroll
  for (int j = 0; j < 2; j++) { nn[j] = n0 + wn + 16*j + col; bb[j] = bo[nn[j]]; }
  #pragma unroll
  for (int i = 0; i < 2; i++)
    #pragma unroll
    for (int r = 0; r < 4; r++) {
      int m = m0 + wm + 16*i + quad*4 + r;
      #pragma unroll
      for (int j = 0; j < 2; j++)
        out[(size_t)m*D_ + nn[j]] = acc[i][j][r] + bb[j];
    }
}

extern "C" void kernel_launch(void* const* d_in, const int* in_sizes, int n_in,
                              void* d_out, int out_size, void* d_ws, size_t ws_size,
                              hipStream_t stream)
{
  const float* q    = (const float*)d_in[0];
  const float* k    = (const float*)d_in[1];
  const float* v    = (const float*)d_in[2];
  const float* mask = (const float*)d_in[3];
  const float* Wq   = (const float*)d_in[4];
  const float* bq   = (const float*)d_in[5];
  const float* Wk   = (const float*)d_in[6];
  const float* bk   = (const float*)d_in[7];
  const float* Wv   = (const float*)d_in[8];
  const float* bv   = (const float*)d_in[9];
  const float* Wo   = (const float*)d_in[10];
  const float* bo   = (const float*)d_in[11];

  const size_t XN = (size_t)M_ * D_;
  const size_t WN = (size_t)D_ * D_;
  const size_t HN = (size_t)BH_ * S_ * DH_;

  char* ws = (char*)d_ws;
  __bf16* Xq  = (__bf16*)ws;                 ws += XN * 2;
  __bf16* Xk  = (__bf16*)ws;                 ws += XN * 2;
  __bf16* Xv  = (__bf16*)ws;                 ws += XN * 2;
  __bf16* Wqb = (__bf16*)ws;                 ws += WN * 2;
  __bf16* Wkb = (__bf16*)ws;                 ws += WN * 2;
  __bf16* Wvb = (__bf16*)ws;                 ws += WN * 2;
  __bf16* Wob = (__bf16*)ws;                 ws += WN * 2;
  __bf16* qfb = (__bf16*)ws;                 ws += HN * 2;
  __bf16* kfb = (__bf16*)ws;                 ws += HN * 2;
  __bf16* vfb = (__bf16*)ws;                 ws += HN * 2;
  __bf16* aob = (__bf16*)ws;                 ws += XN * 2;
  // em (8.4 MB) aliases Xq+Xk (12 MB) — dead after qkv_gemm; em_kernel runs after it.
  __bf16* emb = Xq;

  convert_kernel<<<dim3(3072, 7), 256, 0, stream>>>(
      q, k, v, Wq, Wk, Wv, Wo, Xq, Xk, Xv, Wqb, Wkb, Wvb, Wob);
  qkv_gemm<<<dim3(12, 32, 3), 256, 0, stream>>>(
      Xq, Xk, Xv, Wqb, Wkb, Wvb, bq, bk, bv, qfb, kfb, vfb);
  em_kernel<<<dim3(2048), 256, 0, stream>>>(mask, emb);
  attn_kernel<<<dim3(16, 24), 512, 0, stream>>>(qfb, kfb, vfb, emb, aob);
  out_gemm<<<dim3(12, 64), 256, 0, stream>>>(aob, Wob, bo, (float*)d_out);
}

// Round 4
// 239.545 us; speedup vs baseline: 1.1841x; 1.0568x over previous
//
#include <hip/hip_runtime.h>
#include <hip/hip_bf16.h>

#define B_ 2
#define S_ 2048
#define D_ 768
#define H_ 12
#define DH_ 64
#define M_ (B_*S_)     // 4096
#define BH_ (B_*H_)    // 24

typedef __bf16 v8bf __attribute__((ext_vector_type(8)));
typedef __bf16 v4bf __attribute__((ext_vector_type(4)));
typedef float  v4f  __attribute__((ext_vector_type(4)));

static __device__ __forceinline__ v4f mfma16(v8bf a, v8bf b, v4f c) {
  return __builtin_amdgcn_mfma_f32_16x16x32_bf16(a, b, c, 0, 0, 0);
}

// async global->LDS, 16 B/lane; dest = wave-uniform base + lane*16
static __device__ __forceinline__ void gload_lds16(const __bf16* g, __bf16* l) {
  __builtin_amdgcn_global_load_lds(
      (const __attribute__((address_space(1))) unsigned int*)g,
      (__attribute__((address_space(3))) unsigned int*)l,
      16, 0, 0);
}

#define C1_ 0.18033688011112042f   // log2(e)/sqrt(DH)

// ---------------- fp32 -> bf16 conversion ----------------
__global__ __launch_bounds__(256) void convert_kernel(
    const float* __restrict__ q, const float* __restrict__ k, const float* __restrict__ v,
    const float* __restrict__ Wq, const float* __restrict__ Wk,
    const float* __restrict__ Wv, const float* __restrict__ Wo,
    __bf16* __restrict__ Xq, __bf16* __restrict__ Xk, __bf16* __restrict__ Xv,
    __bf16* __restrict__ Wqb, __bf16* __restrict__ Wkb,
    __bf16* __restrict__ Wvb, __bf16* __restrict__ Wob)
{
  const float* src; __bf16* dst; int n;
  switch (blockIdx.y) {
    case 0: src = q;  dst = Xq;  n = M_*D_; break;
    case 1: src = k;  dst = Xk;  n = M_*D_; break;
    case 2: src = v;  dst = Xv;  n = M_*D_; break;
    case 3: src = Wq; dst = Wqb; n = D_*D_; break;
    case 4: src = Wk; dst = Wkb; n = D_*D_; break;
    case 5: src = Wv; dst = Wvb; n = D_*D_; break;
    default: src = Wo; dst = Wob; n = D_*D_; break;
  }
  int n4 = n >> 2;
  for (int i = blockIdx.x*blockDim.x + threadIdx.x; i < n4; i += gridDim.x*blockDim.x) {
    float4 x = ((const float4*)src)[i];
    v4bf y;
    y[0] = (__bf16)x.x; y[1] = (__bf16)x.y; y[2] = (__bf16)x.z; y[3] = (__bf16)x.w;
    ((v4bf*)dst)[i] = y;
  }
}

// ---------------- em precompute: em = bf16(exp2(C1*mask)) in attn-lane order ----------------
// flat t = (((qt*64 + kt)*8 + w)*64 + L); elem t*8 + (krow*4 + r) holds
// exp2(C1*mask[qt*128 + w*16 + (L&15)][kt*32 + krow*16 + (L>>4)*4 + r]).
__global__ __launch_bounds__(256) void em_kernel(
    const float* __restrict__ mask, __bf16* __restrict__ em)
{
  int t = blockIdx.x*256 + threadIdx.x;        // 0 .. 524287
  int L = t & 63; int rest = t >> 6;
  int w = rest & 7; rest >>= 3;
  int kt = rest & 63; rest >>= 6;
  int qt = rest;                                // 0..15
  int row = qt*128 + w*16 + (L & 15);
  int key0 = kt*32 + ((L >> 4) << 2);
  const float* mp = mask + (size_t)row*S_ + key0;
  float4 m0 = *(const float4*)mp;
  float4 m1 = *(const float4*)(mp + 16);
  v8bf e;
  e[0] = (__bf16)exp2f(C1_*m0.x); e[1] = (__bf16)exp2f(C1_*m0.y);
  e[2] = (__bf16)exp2f(C1_*m0.z); e[3] = (__bf16)exp2f(C1_*m0.w);
  e[4] = (__bf16)exp2f(C1_*m1.x); e[5] = (__bf16)exp2f(C1_*m1.y);
  e[6] = (__bf16)exp2f(C1_*m1.z); e[7] = (__bf16)exp2f(C1_*m1.w);
  *(v8bf*)(em + (size_t)t*8) = e;
}

// ---------------- 128x128 NT-GEMM core, counted-vmcnt 3-buffer pipeline ----------------
// C[128x128] = A[128xD] @ W[128xD]^T.  4 waves, acc 4x4 per wave (16 MFMA/step).
// Per K-step each lane issues EXACTLY 4 global_load_lds (16 B) for step ks+2; top of
// step: s_waitcnt vmcnt(4) (retires step ks's 4, leaves ks+1's in flight ACROSS the
// raw s_barrier).  Buffer (ks+2)%3 is safe: its readers finished at step ks-1, before
// barrier ks.  LDS = 3 x 16 KB.
static __device__ __forceinline__ void gemm128_pipe(
    const __bf16* __restrict__ A, const __bf16* __restrict__ W,
    int m0, int n0, __bf16* lds, v4f acc[4][4])
{
  const int lane = threadIdx.x & 63;
  const int wave = threadIdx.x >> 6;
  const int r16 = lane & 15;
  const int kc8 = (lane >> 4) << 3;
  const int ia = (wave >> 1) << 2;    // a-fragment base (0 or 4, of 8)
  const int ib = (wave & 1) << 2;     // b-fragment base (0 or 4, of 8)

  const __bf16* gsrc[4]; int ldo[4];
  #pragma unroll
  for (int t = 0; t < 4; t++) {
    int fb = wave*4 + t;
    gsrc[t] = (fb < 8)
        ? A + (size_t)(m0 + fb*16 + r16)*D_ + kc8
        : W + (size_t)(n0 + (fb - 8)*16 + r16)*D_ + kc8;
    ldo[t] = fb << 9;
  }

  // prologue: stage k-steps 0 (buf0) and 1 (buf1), issue order pinned
  asm volatile("" ::: "memory");
  #pragma unroll
  for (int t = 0; t < 4; t++) gload_lds16(gsrc[t], lds + ldo[t]);
  asm volatile("" ::: "memory");
  #pragma unroll
  for (int t = 0; t < 4; t++) gload_lds16(gsrc[t] + 32, lds + 8192 + ldo[t]);
  asm volatile("" ::: "memory");

#define G_STEP(CUR, NXTB, KC, ISSUE, WSTR) { \
    asm volatile("s_waitcnt vmcnt(" WSTR ")" ::: "memory"); \
    __builtin_amdgcn_s_barrier(); \
    asm volatile("" ::: "memory"); \
    if (ISSUE) { \
      _Pragma("unroll") \
      for (int t = 0; t < 4; t++) \
        gload_lds16(gsrc[t] + (KC), lds + (NXTB)*8192 + ldo[t]); \
    } \
    const __bf16* buf = lds + (CUR)*8192; \
    v8bf a[4], b[4]; \
    _Pragma("unroll") \
    for (int i = 0; i < 4; i++) a[i] = *(const v8bf*)(buf + ((ia+i) << 9) + lane*8); \
    _Pragma("unroll") \
    for (int j = 0; j < 4; j++) b[j] = *(const v8bf*)(buf + ((8+ib+j) << 9) + lane*8); \
    _Pragma("unroll") \
    for (int i = 0; i < 4; i++) \
      _Pragma("unroll") \
      for (int j = 0; j < 4; j++) \
        acc[i][j] = mfma16(a[i], b[j], acc[i][j]); \
  }

  // D_/32 = 24 steps total; steps 0..17 in a x3-unrolled loop, 18..23 as tail.
  #pragma unroll 1
  for (int ks0 = 0; ks0 < 18; ks0 += 3) {
    G_STEP(0, 2, (ks0+2)*32, true, "4");
    G_STEP(1, 0, (ks0+3)*32, true, "4");
    G_STEP(2, 1, (ks0+4)*32, true, "4");
  }
  G_STEP(0, 2, 20*32, true,  "4");   // ks=18, issues 20
  G_STEP(1, 0, 21*32, true,  "4");   // ks=19, issues 21
  G_STEP(2, 1, 22*32, true,  "4");   // ks=20, issues 22
  G_STEP(0, 2, 23*32, true,  "4");   // ks=21, issues 23
  G_STEP(1, 0, 0,     false, "4");   // ks=22: leaves 23's 4 in flight
  G_STEP(2, 0, 0,     false, "0");   // ks=23: drain
#undef G_STEP
}

// ---------------- QKV projection (128x128 tiles) -> FRAGMENT-ORDERED qf/kf/vf ----------------
__global__ __launch_bounds__(256, 3) void qkv_gemm(
    const __bf16* __restrict__ Xq, const __bf16* __restrict__ Xk, const __bf16* __restrict__ Xv,
    const __bf16* __restrict__ Wqb, const __bf16* __restrict__ Wkb, const __bf16* __restrict__ Wvb,
    const float* __restrict__ bq, const float* __restrict__ bk, const float* __restrict__ bv,
    __bf16* __restrict__ qf, __bf16* __restrict__ kf, __bf16* __restrict__ vf)
{
  __shared__ __bf16 lds[3*8192];   // 48 KB
  const int mode = blockIdx.z;
  const __bf16* A = (mode == 0) ? Xq : (mode == 1) ? Xk : Xv;
  const __bf16* W = (mode == 0) ? Wqb : (mode == 1) ? Wkb : Wvb;
  const float* bias = (mode == 0) ? bq : (mode == 1) ? bk : bv;
  const int m0 = blockIdx.y << 7, n0 = blockIdx.x << 7;
  v4f acc[4][4];
  #pragma unroll
  for (int i = 0; i < 4; i++)
    #pragma unroll
    for (int j = 0; j < 4; j++) { v4f z = {0.f,0.f,0.f,0.f}; acc[i][j] = z; }
  gemm128_pipe(A, W, m0, n0, lds, acc);

  const int lane = threadIdx.x & 63;
  const int wave = threadIdx.x >> 6;
  const int wm = (wave >> 1) << 6, wn = (wave & 1) << 6;
  const int col = lane & 15, quad = lane >> 4;
  float bb[4]; int nn[4];
  #pragma unroll
  for (int j = 0; j < 4; j++) { nn[j] = n0 + wn + 16*j + col; bb[j] = bias[nn[j]]; }

  if (mode < 2) {
    __bf16* dst = (mode == 0) ? qf : kf;
    const float sc = (mode == 0) ? C1_ : 1.0f;
    #pragma unroll
    for (int i = 0; i < 4; i++)
      #pragma unroll
      for (int r = 0; r < 4; r++) {
        int m = m0 + wm + 16*i + quad*4 + r;
        int batch = m >> 11, s = m & (S_-1);
        #pragma unroll
        for (int j = 0; j < 4; j++) {
          int n = nn[j];
          int h = n >> 6, dd = n & 63;
          size_t flat = (((size_t)(batch*H_ + h)*128 + (s >> 4))*2 + (dd >> 5))*512
                      + ((((dd >> 3) & 3)*16 + (s & 15)) << 3) + (dd & 7);
          dst[flat] = (__bf16)((acc[i][j][r] + bb[j]) * sc);
        }
      }
  } else {
    #pragma unroll
    for (int i = 0; i < 4; i++) {
      int mbase = m0 + wm + 16*i + quad*4;
      int batch = mbase >> 11, s0 = mbase & (S_-1);
      #pragma unroll
      for (int j = 0; j < 4; j++) {
        int n = nn[j];
        int h = n >> 6, dd = n & 63;
        v4bf pk;
        #pragma unroll
        for (int r = 0; r < 4; r++) pk[r] = (__bf16)(acc[i][j][r] + bb[j]);
        size_t flat = (((size_t)(batch*H_ + h)*64 + (s0 >> 5))*4 + (dd >> 4))*512
                    + ((((s0 >> 3) & 3)*16 + (dd & 15)) << 3) + (s0 & 7);
        *(v4bf*)(vf + flat) = pk;
      }
    }
  }
}

// ---------------- flash attention: 128 q/block, 8 waves, LDS-shared K/V ----------------
// Counted-vmcnt pipeline (T3/T4): 4 LDS K/V buffers, 2 tiles of lookahead.  Per step each
// lane issues EXACTLY 2 VMEM ops for tile kt+2 (1 global_load_lds of its K-or-V slice +
// 1 em global load into rotating regs ef0..ef3).  Top of each step: s_waitcnt vmcnt(2)
// (waits only tile kt's pair; tile kt+1's pair stays in flight ACROSS the raw s_barrier).
__global__ __launch_bounds__(512, 2) void attn_kernel(
    const __bf16* __restrict__ qf, const __bf16* __restrict__ kf, const __bf16* __restrict__ vf,
    const __bf16* __restrict__ em, __bf16* __restrict__ ao)
{
  __shared__ __bf16 kv[4][2][2048];   // [buf][K=0/V=1][32 keys x 64 dh]  32 KB
  __shared__ __bf16 plds[8][16][40];  // per-wave P transpose, padded     10 KB

  const int bh = blockIdx.y;
  const int qt = blockIdx.x;                     // 0..15  (128-query tile)
  const int wave = threadIdx.x >> 6, lane = threadIdx.x & 63;
  const int col = lane & 15, quad = lane >> 4, koff = quad << 3;
  const int batch = bh / H_, h = bh % H_;
  const __bf16* qfb = qf + (size_t)bh * (S_*DH_);
  const __bf16* kfb = kf + (size_t)bh * (S_*DH_);
  const __bf16* vfb = vf + (size_t)bh * (S_*DH_);
  const __bf16* emw = em + (size_t)qt * 262144 + wave*512 + lane*8;  // + kt*4096 per step
  __bf16 (*pt)[40] = plds[wave];

  // staging assignment: waves 0-3 -> K slice, waves 4-7 -> V slice (512 elems each)
  const __bf16* gsrc = ((wave < 4) ? kfb : vfb) + ((wave & 3) << 9) + lane*8;
  __bf16* kvd[4];
  #pragma unroll
  for (int b = 0; b < 4; b++) kvd[b] = &kv[b][wave >> 2][(wave & 3) << 9];

  // Q fragments for this wave's 16 queries (s16 block = qt*8 + wave)
  const __bf16* qblk = qfb + (size_t)(qt*8 + wave)*1024;
  v8bf Qf0 = *(const v8bf*)(qblk + lane*8);
  v8bf Qf1 = *(const v8bf*)(qblk + 512 + lane*8);

  v4f O[4];
  #pragma unroll
  for (int f = 0; f < 4; f++) { v4f z = {0.f,0.f,0.f,0.f}; O[f] = z; }
  float li = 0.f;

  // ---- pipelined prologue: stage tiles 0 and 1, em regs 0 and 1 (order pinned) ----
  asm volatile("" ::: "memory");
  gload_lds16(gsrc, kvd[0]);
  v8bf ef0 = *(const v8bf*)(emw);
  asm volatile("" ::: "memory");
  gload_lds16(gsrc + 2048, kvd[1]);
  v8bf ef1 = *(const v8bf*)(emw + 4096);
  v8bf ef2, ef3;

#define ATT_STEP(P, EFC, EFN, ISSUE, WSTR) \
  { \
    asm volatile("s_waitcnt vmcnt(" WSTR ")" ::: "memory"); \
    __builtin_amdgcn_s_barrier(); \
    asm volatile("" ::: "memory"); \
    if (ISSUE) { \
      const int nkt = kt0 + (P) + 2; \
      gload_lds16(gsrc + (size_t)nkt*2048, kvd[((P)+2)&3]); \
      EFN = *(const v8bf*)(emw + (size_t)nkt*4096); \
    } \
    const __bf16* Kb = kv[(P)&3][0]; \
    const __bf16* Vb = kv[(P)&3][1]; \
    v8bf Ka0 = *(const v8bf*)(Kb + lane*8); \
    v8bf Ka1 = *(const v8bf*)(Kb + 512 + lane*8); \
    v8bf Ka2 = *(const v8bf*)(Kb + 1024 + lane*8); \
    v8bf Ka3 = *(const v8bf*)(Kb + 1536 + lane*8); \
    v4f s0 = {0.f,0.f,0.f,0.f}, s1 = {0.f,0.f,0.f,0.f}; \
    s0 = mfma16(Ka0, Qf0, s0); s0 = mfma16(Ka1, Qf1, s0); \
    s1 = mfma16(Ka2, Qf0, s1); s1 = mfma16(Ka3, Qf1, s1); \
    float p[8], rs = 0.f; \
    _Pragma("unroll") \
    for (int j = 0; j < 4; j++) { \
      p[j]   = exp2f(s0[j]) * (float)EFC[j]; \
      p[4+j] = exp2f(s1[j]) * (float)EFC[4+j]; \
    } \
    _Pragma("unroll") \
    for (int j = 0; j < 8; j++) rs += p[j]; \
    li += rs; \
    v4bf pk0, pk1; \
    _Pragma("unroll") \
    for (int r = 0; r < 4; r++) { pk0[r] = (__bf16)p[r]; pk1[r] = (__bf16)p[4+r]; } \
    *(v4bf*)(&pt[col][quad*4])      = pk0; \
    *(v4bf*)(&pt[col][16 + quad*4]) = pk1; \
    v8bf Pf = *(const v8bf*)(&pt[col][koff]); \
    v8bf Vf0 = *(const v8bf*)(Vb + lane*8); \
    v8bf Vf1 = *(const v8bf*)(Vb + 512 + lane*8); \
    v8bf Vf2 = *(const v8bf*)(Vb + 1024 + lane*8); \
    v8bf Vf3 = *(const v8bf*)(Vb + 1536 + lane*8); \
    O[0] = mfma16(Vf0, Pf, O[0]); \
    O[1] = mfma16(Vf1, Pf, O[1]); \
    O[2] = mfma16(Vf2, Pf, O[2]); \
    O[3] = mfma16(Vf3, Pf, O[3]); \
  }

  #pragma unroll 1
  for (int kt0 = 0; kt0 < 60; kt0 += 4) {
    ATT_STEP(0, ef0, ef2, true, "2");
    ATT_STEP(1, ef1, ef3, true, "2");
    ATT_STEP(2, ef2, ef0, true, "2");
    ATT_STEP(3, ef3, ef1, true, "2");
  }
  {
    const int kt0 = 60;
    ATT_STEP(0, ef0, ef2, true,  "2");   // kt=60, issues pair 62
    ATT_STEP(1, ef1, ef3, true,  "2");   // kt=61, issues pair 63
    ATT_STEP(2, ef2, ef0, false, "2");   // kt=62: outstanding {62,63} -> wait leaves 63
    ATT_STEP(3, ef3, ef1, false, "0");   // kt=63: drain
  }
#undef ATT_STEP

  // ---- epilogue: per-wave complete rows ----
  float rs = li;
  rs += __shfl_xor(rs, 16);
  rs += __shfl_xor(rs, 32);
  float invl = 1.f / rs;
  const int qg = (qt << 7) + (wave << 4) + col;
  __bf16* orow = ao + ((size_t)batch*S_ + qg)*D_ + h*DH_ + quad*4;
  #pragma unroll
  for (int f = 0; f < 4; f++) {
    v4bf o;
    #pragma unroll
    for (int r = 0; r < 4; r++) o[r] = (__bf16)(O[f][r] * invl);
    *(v4bf*)(orow + f*16) = o;
  }
}

// ---------------- output projection (128x128 tiles): fp32 out ----------------
__global__ __launch_bounds__(256, 3) void out_gemm(
    const __bf16* __restrict__ Ao, const __bf16* __restrict__ Wob,
    const float* __restrict__ bo, float* __restrict__ out)
{
  __shared__ __bf16 lds[3*8192];   // 48 KB
  const int m0 = blockIdx.y << 7, n0 = blockIdx.x << 7;
  v4f acc[4][4];
  #pragma unroll
  for (int i = 0; i < 4; i++)
    #pragma unroll
    for (int j = 0; j < 4; j++) { v4f z = {0.f,0.f,0.f,0.f}; acc[i][j] = z; }
  gemm128_pipe(Ao, Wob, m0, n0, lds, acc);

  const int lane = threadIdx.x & 63;
  const int wave = threadIdx.x >> 6;
  const int wm = (wave >> 1) << 6, wn = (wave & 1) << 6;
  const int col = lane & 15, quad = lane >> 4;
  float bb[4]; int nn[4];
  #pragma unroll
  for (int j = 0; j < 4; j++) { nn[j] = n0 + wn + 16*j + col; bb[j] = bo[nn[j]]; }
  #pragma unroll
  for (int i = 0; i < 4; i++)
    #pragma unroll
    for (int r = 0; r < 4; r++) {
      int m = m0 + wm + 16*i + quad*4 + r;
      #pragma unroll
      for (int j = 0; j < 4; j++)
        out[(size_t)m*D_ + nn[j]] = acc[i][j][r] + bb[j];
    }
}

extern "C" void kernel_launch(void* const* d_in, const int* in_sizes, int n_in,
                              void* d_out, int out_size, void* d_ws, size_t ws_size,
                              hipStream_t stream)
{
  const float* q    = (const float*)d_in[0];
  const float* k    = (const float*)d_in[1];
  const float* v    = (const float*)d_in[2];
  const float* mask = (const float*)d_in[3];
  const float* Wq   = (const float*)d_in[4];
  const float* bq   = (const float*)d_in[5];
  const float* Wk   = (const float*)d_in[6];
  const float* bk   = (const float*)d_in[7];
  const float* Wv   = (const float*)d_in[8];
  const float* bv   = (const float*)d_in[9];
  const float* Wo   = (const float*)d_in[10];
  const float* bo   = (const float*)d_in[11];

  const size_t XN = (size_t)M_ * D_;
  const size_t WN = (size_t)D_ * D_;
  const size_t HN = (size_t)BH_ * S_ * DH_;

  char* ws = (char*)d_ws;
  __bf16* Xq  = (__bf16*)ws;                 ws += XN * 2;
  __bf16* Xk  = (__bf16*)ws;                 ws += XN * 2;
  __bf16* Xv  = (__bf16*)ws;                 ws += XN * 2;
  __bf16* Wqb = (__bf16*)ws;                 ws += WN * 2;
  __bf16* Wkb = (__bf16*)ws;                 ws += WN * 2;
  __bf16* Wvb = (__bf16*)ws;                 ws += WN * 2;
  __bf16* Wob = (__bf16*)ws;                 ws += WN * 2;
  __bf16* qfb = (__bf16*)ws;                 ws += HN * 2;
  __bf16* kfb = (__bf16*)ws;                 ws += HN * 2;
  __bf16* vfb = (__bf16*)ws;                 ws += HN * 2;
  __bf16* aob = (__bf16*)ws;                 ws += XN * 2;
  // em (8.4 MB) aliases Xq+Xk (12 MB) — dead after qkv_gemm; em_kernel runs after it.
  __bf16* emb = Xq;

  convert_kernel<<<dim3(768, 7), 256, 0, stream>>>(
      q, k, v, Wq, Wk, Wv, Wo, Xq, Xk, Xv, Wqb, Wkb, Wvb, Wob);
  qkv_gemm<<<dim3(6, 32, 3), 256, 0, stream>>>(
      Xq, Xk, Xv, Wqb, Wkb, Wvb, bq, bk, bv, qfb, kfb, vfb);
  em_kernel<<<dim3(2048), 256, 0, stream>>>(mask, emb);
  attn_kernel<<<dim3(16, 24), 512, 0, stream>>>(qfb, kfb, vfb, emb, aob);
  out_gemm<<<dim3(6, 32), 256, 0, stream>>>(aob, Wob, bo, (float*)d_out);
}